// Round 2
// baseline (506.099 us; speedup 1.0000x reference)
//
#include <hip/hip_runtime.h>

#define S_LEN 2048
#define DMODEL 1024
#define NHEADS 16
#define MLPDIM 4096

typedef float f32x4 __attribute__((ext_vector_type(4)));
typedef __bf16 bf16x8 __attribute__((ext_vector_type(8)));
typedef __bf16 bf16x4 __attribute__((ext_vector_type(4)));

__device__ __forceinline__ void gload_lds16(const void* gsrc, void* ldst) {
  __builtin_amdgcn_global_load_lds(
      (const __attribute__((address_space(1))) void*)gsrc,
      (__attribute__((address_space(3))) void*)ldst, 16, 0, 0);
}

// ---------------- transpose + f32->bf16 cast: in [K][N] f32 -> out [N][K] bf16
__global__ __launch_bounds__(256) void transpose_cast_k(
    const float* __restrict__ in, __bf16* __restrict__ out, int K, int N) {
  __shared__ float tile[32][33];
  int n0 = blockIdx.x * 32, k0 = blockIdx.y * 32;
  int tx = threadIdx.x & 31, ty = threadIdx.x >> 5;
#pragma unroll
  for (int r = 0; r < 32; r += 8)
    tile[r + ty][tx] = in[(size_t)(k0 + r + ty) * N + n0 + tx];
  __syncthreads();
#pragma unroll
  for (int r = 0; r < 32; r += 8)
    out[(size_t)(n0 + r + ty) * K + k0 + tx] = (__bf16)tile[tx][r + ty];
}

// ---------------- bf16 transpose of V slice: qkv[4096][3072] cols 2048.. -> vt[b][1024][2048]
__global__ __launch_bounds__(256) void vtrans_k(
    const __bf16* __restrict__ qkv, __bf16* __restrict__ vt) {
  __shared__ __bf16 tile[32][33];
  int s0 = blockIdx.x * 32, c0 = blockIdx.y * 32, b = blockIdx.z;
  int tx = threadIdx.x & 31, ty = threadIdx.x >> 5;
#pragma unroll
  for (int r = 0; r < 32; r += 8)
    tile[r + ty][tx] = qkv[(size_t)(b * S_LEN + s0 + r + ty) * 3072 + 2048 + c0 + tx];
  __syncthreads();
#pragma unroll
  for (int r = 0; r < 32; r += 8)
    vt[(size_t)(b * 1024 + c0 + r + ty) * S_LEN + s0 + tx] = tile[tx][r + ty];
}

__global__ __launch_bounds__(256) void concat3_k(
    const float* __restrict__ a, const float* __restrict__ b,
    const float* __restrict__ c, float* __restrict__ dst) {
  int i = blockIdx.x * 256 + threadIdx.x;
  if (i < 1024) dst[i] = a[i];
  else if (i < 2048) dst[i] = b[i - 1024];
  else if (i < 3072) dst[i] = c[i - 2048];
}

// ---------------- RMSNorm: x f32 [rows][1024] -> bf16, * scale
__global__ __launch_bounds__(256) void rmsnorm_k(
    const float* __restrict__ x, const float* __restrict__ scale,
    __bf16* __restrict__ out) {
  int row = blockIdx.x, tid = threadIdx.x;
  f32x4 v = ((const f32x4*)(x + (size_t)row * DMODEL))[tid];
  float ss = v[0] * v[0] + v[1] * v[1] + v[2] * v[2] + v[3] * v[3];
#pragma unroll
  for (int off = 1; off < 64; off <<= 1) ss += __shfl_xor(ss, off, 64);
  __shared__ float part[4];
  if ((tid & 63) == 0) part[tid >> 6] = ss;
  __syncthreads();
  float tot = part[0] + part[1] + part[2] + part[3];
  float r = rsqrtf(tot * (1.0f / DMODEL) + 1e-6f);
  f32x4 s4 = ((const f32x4*)scale)[tid];
  bf16x4 o;
#pragma unroll
  for (int e = 0; e < 4; ++e) o[e] = (__bf16)(v[e] * r * s4[e]);
  ((bf16x4*)out)[(size_t)row * (DMODEL / 4) + tid] = o;
}

// ---------------- GEMM: C[M][N] = A[M][K](bf16) @ Bt[N][K]^T(bf16) + bias
template <int OUT_BF16, int RESID, int SILU>
__global__ __launch_bounds__(256, 2) void gemm_bt(
    const __bf16* __restrict__ A, const __bf16* __restrict__ Bt,
    const float* __restrict__ bias, const float* __restrict__ resid,
    const __bf16* __restrict__ aux, void* __restrict__ Cout,
    int M, int N, int K) {
  __shared__ __attribute__((aligned(16))) __bf16 As[128 * 64];
  __shared__ __attribute__((aligned(16))) __bf16 Bs[128 * 64];
  int tid = threadIdx.x, lane = tid & 63, wave = tid >> 6;
  int l15 = lane & 15, g4 = lane >> 4;
  int bm = blockIdx.y * 128, bn = blockIdx.x * 128;
  int wr = wave >> 1, wc = wave & 1;
  f32x4 acc[4][4] = {};
  int srow = lane >> 3, scol = (lane & 7) * 8;
  const __bf16* Abase = A + (size_t)bm * K;
  const __bf16* Bbase = Bt + (size_t)bn * K;

  for (int k0 = 0; k0 < K; k0 += 64) {
#pragma unroll
    for (int i = 0; i < 4; ++i) {
      int c = wave * 4 + i;
      int row = c * 8 + srow;
      gload_lds16(Abase + (size_t)row * K + k0 + scol, As + c * 512);
      gload_lds16(Bbase + (size_t)row * K + k0 + scol, Bs + c * 512);
    }
    __syncthreads();
#pragma unroll
    for (int ks = 0; ks < 2; ++ks) {
      bf16x8 af[4], bfr[4];
#pragma unroll
      for (int m = 0; m < 4; ++m)
        af[m] = *(const bf16x8*)(As + (wr * 64 + m * 16 + l15) * 64 + ks * 32 + g4 * 8);
#pragma unroll
      for (int n = 0; n < 4; ++n)
        bfr[n] = *(const bf16x8*)(Bs + (wc * 64 + n * 16 + l15) * 64 + ks * 32 + g4 * 8);
#pragma unroll
      for (int m = 0; m < 4; ++m)
#pragma unroll
        for (int n = 0; n < 4; ++n)
          acc[m][n] = __builtin_amdgcn_mfma_f32_16x16x32_bf16(af[m], bfr[n], acc[m][n], 0, 0, 0);
    }
    __syncthreads();
  }
  int r0 = bm + wr * 64 + g4 * 4;
  int c0 = bn + wc * 64 + l15;
#pragma unroll
  for (int n = 0; n < 4; ++n) {
    int c = c0 + n * 16;
    float bv = bias[c];
#pragma unroll
    for (int m = 0; m < 4; ++m) {
      int rb = r0 + m * 16;
#pragma unroll
      for (int rg = 0; rg < 4; ++rg) {
        int r = rb + rg;
        size_t idx = (size_t)r * N + c;
        float v = acc[m][n][rg] + bv;
        if (SILU) {
          float gg = (float)aux[idx];
          v *= gg / (1.0f + __expf(-gg));
        }
        if (RESID) v += resid[idx];
        if (OUT_BF16) ((__bf16*)Cout)[idx] = (__bf16)v;
        else ((float*)Cout)[idx] = v;
      }
    }
  }
}

// ---------------- causal flash attention, LDS-free, one wave per 16 q-rows.
// Swapped QK^T: mfma(K,Q) -> lane holds S[key][q=l15] for 16 keys.
// P stays in-register (custom sigma shared with VT B-fragments).
#define SCL2E 0.180336879f  /* 0.125 * log2(e) */
__global__ __launch_bounds__(256, 4) void attn_k(
    const __bf16* __restrict__ qkv, const __bf16* __restrict__ vt,
    __bf16* __restrict__ ao) {
  int lane = threadIdx.x & 63, w = threadIdx.x >> 6;
  int l15 = lane & 15, g4 = lane >> 4;
  int bh = blockIdx.x;               // bh on fast grid dim: XCD = bh%8 (L2 locality)
  int b = bh >> 4, h = bh & 15;
  int qt = 31 - blockIdx.y;          // longest q-tiles dispatch first
  int qw = qt * 64 + w * 16;
  const __bf16* qkvb = qkv + (size_t)b * S_LEN * 3072 + h * 64;
  const __bf16* vtb = vt + (size_t)b * 1024 * S_LEN + (size_t)(h * 64) * S_LEN;

  // Q fragment (B-operand): q = qw + l15, d = 32ks + 8g4 + e
  bf16x8 qf[2];
#pragma unroll
  for (int ks = 0; ks < 2; ++ks)
    qf[ks] = *(const bf16x8*)(qkvb + (size_t)(qw + l15) * 3072 + 32 * ks + 8 * g4);

  f32x4 oa[4] = {};                  // oa[dn][rg]: O[q=4g4+rg][d=dn*16+l15]
  float mrow = -1e30f, lrow = 0.f;   // for q = qw + l15, log2 domain
  int q = qw + l15;
  int nt = (qw + 16 + 63) / 64;

  for (int t = 0; t < nt; ++t) {
    int kvb = t * 64;
    const __bf16* kbase = qkvb + 1024 + (size_t)kvb * 3072;
    f32x4 sa[4] = {};                // sa[n][rg]: key = kvb+n*16+4g4+rg
#pragma unroll
    for (int ks = 0; ks < 2; ++ks) {
      bf16x8 kf[4];
#pragma unroll
      for (int n = 0; n < 4; ++n)
        kf[n] = *(const bf16x8*)(kbase + (size_t)(n * 16 + l15) * 3072 + 32 * ks + 8 * g4);
#pragma unroll
      for (int n = 0; n < 4; ++n)
        sa[n] = __builtin_amdgcn_mfma_f32_16x16x32_bf16(kf[n], qf[ks], sa[n], 0, 0, 0);
    }
    // online softmax in log2 domain
    float nmx = -1e30f;
#pragma unroll
    for (int n = 0; n < 4; ++n)
#pragma unroll
      for (int rg = 0; rg < 4; ++rg) {
        int key = kvb + n * 16 + 4 * g4 + rg;
        float s = sa[n][rg] * SCL2E;
        s = (key <= q) ? s : -1e30f;
        sa[n][rg] = s;
        nmx = fmaxf(nmx, s);
      }
    nmx = fmaxf(nmx, __shfl_xor(nmx, 16));
    nmx = fmaxf(nmx, __shfl_xor(nmx, 32));
    float nm = fmaxf(mrow, nmx);
    float sc = exp2f(mrow - nm);
    mrow = nm;
    float rs = 0.f;
    bf16x8 pa[2];                    // A-frag: sigma(g4,e) = 4g4+(e&3)+16*(e>>2)
#pragma unroll
    for (int ks = 0; ks < 2; ++ks)
#pragma unroll
      for (int half = 0; half < 2; ++half) {
        int n = 2 * ks + half;
#pragma unroll
        for (int rg = 0; rg < 4; ++rg) {
          float p = exp2f(sa[n][rg] - nm);
          rs += p;
          pa[ks][half * 4 + rg] = (__bf16)p;
        }
      }
    rs += __shfl_xor(rs, 16);
    rs += __shfl_xor(rs, 32);
    lrow = lrow * sc + rs;
#pragma unroll
    for (int rg = 0; rg < 4; ++rg) {
      float scq = __shfl(sc, 4 * g4 + rg);
#pragma unroll
      for (int dn = 0; dn < 4; ++dn) oa[dn][rg] *= scq;
    }
    // O += P V : vf[e] = VT[d][kvb+32ks+sigma(g4,e)] (two 8B loads)
#pragma unroll
    for (int ks = 0; ks < 2; ++ks)
#pragma unroll
      for (int dn = 0; dn < 4; ++dn) {
        const __bf16* vb = vtb + (size_t)(dn * 16 + l15) * S_LEN + kvb + 32 * ks + 4 * g4;
        bf16x4 v0 = *(const bf16x4*)(vb);
        bf16x4 v1 = *(const bf16x4*)(vb + 16);
        bf16x8 vf;
        vf[0] = v0[0]; vf[1] = v0[1]; vf[2] = v0[2]; vf[3] = v0[3];
        vf[4] = v1[0]; vf[5] = v1[1]; vf[6] = v1[2]; vf[7] = v1[3];
        oa[dn] = __builtin_amdgcn_mfma_f32_16x16x32_bf16(pa[ks], vf, oa[dn], 0, 0, 0);
      }
  }
  // epilogue: O[q'=qw+4g4+rg][d=h*64+dn*16+l15], L redistributed via shfl
  __bf16* aobase = ao + (size_t)b * S_LEN * DMODEL + h * 64;
#pragma unroll
  for (int rg = 0; rg < 4; ++rg) {
    float rl = 1.0f / __shfl(lrow, 4 * g4 + rg);
    int qo = qw + 4 * g4 + rg;
#pragma unroll
    for (int dn = 0; dn < 4; ++dn)
      aobase[(size_t)qo * DMODEL + dn * 16 + l15] = (__bf16)(oa[dn][rg] * rl);
  }
}

// ---------------- host side ----------------
#define OFF_WQKV 0
#define OFF_WO 6291456
#define OFF_WG 8388608
#define OFF_WU 16777216
#define OFF_WD 25165824
#define OFF_BQKV 33554432
#define OFF_H 33570816
#define OFF_QKV 41959424
#define OFF_AO 67125248
#define OFF_G OFF_QKV
#define OFF_T 75513856
#define OFF_VT OFF_T  /* VT lives in tbuf's region; dead before up-GEMM writes tbuf */
#define OFF_X2 109068288

extern "C" void kernel_launch(void* const* d_in, const int* in_sizes, int n_in,
                              void* d_out, int out_size, void* d_ws, size_t ws_size,
                              hipStream_t stream) {
  (void)in_sizes; (void)n_in; (void)out_size; (void)ws_size;
  const float* x = (const float*)d_in[0];
  const float* attn_scale = (const float*)d_in[2];
  const float* q_w = (const float*)d_in[3];
  const float* q_b = (const float*)d_in[4];
  const float* k_w = (const float*)d_in[5];
  const float* k_b = (const float*)d_in[6];
  const float* v_w = (const float*)d_in[7];
  const float* v_b = (const float*)d_in[8];
  const float* o_w = (const float*)d_in[9];
  const float* o_b = (const float*)d_in[10];
  const float* ffn_scale = (const float*)d_in[11];
  const float* gate_w = (const float*)d_in[12];
  const float* gate_b = (const float*)d_in[13];
  const float* up_w = (const float*)d_in[14];
  const float* up_b = (const float*)d_in[15];
  const float* down_w = (const float*)d_in[16];
  const float* down_b = (const float*)d_in[17];

  char* ws = (char*)d_ws;
  __bf16* wqkv = (__bf16*)(ws + OFF_WQKV);
  __bf16* wo = (__bf16*)(ws + OFF_WO);
  __bf16* wg = (__bf16*)(ws + OFF_WG);
  __bf16* wu = (__bf16*)(ws + OFF_WU);
  __bf16* wd = (__bf16*)(ws + OFF_WD);
  float* bqkv = (float*)(ws + OFF_BQKV);
  __bf16* hbuf = (__bf16*)(ws + OFF_H);
  __bf16* qkvbuf = (__bf16*)(ws + OFF_QKV);
  __bf16* aobuf = (__bf16*)(ws + OFF_AO);
  __bf16* gbuf = (__bf16*)(ws + OFF_G);
  __bf16* tbuf = (__bf16*)(ws + OFF_T);
  __bf16* vtbuf = (__bf16*)(ws + OFF_VT);
  float* x2 = (float*)(ws + OFF_X2);

  dim3 blk(256);
  // weight prep
  transpose_cast_k<<<dim3(32, 32), blk, 0, stream>>>(q_w, wqkv, 1024, 1024);
  transpose_cast_k<<<dim3(32, 32), blk, 0, stream>>>(k_w, wqkv + 1024 * 1024, 1024, 1024);
  transpose_cast_k<<<dim3(32, 32), blk, 0, stream>>>(v_w, wqkv + 2 * 1024 * 1024, 1024, 1024);
  transpose_cast_k<<<dim3(32, 32), blk, 0, stream>>>(o_w, wo, 1024, 1024);
  transpose_cast_k<<<dim3(128, 32), blk, 0, stream>>>(gate_w, wg, 1024, 4096);
  transpose_cast_k<<<dim3(128, 32), blk, 0, stream>>>(up_w, wu, 1024, 4096);
  transpose_cast_k<<<dim3(32, 128), blk, 0, stream>>>(down_w, wd, 4096, 1024);
  concat3_k<<<12, blk, 0, stream>>>(q_b, k_b, v_b, bqkv);
  // attn path
  rmsnorm_k<<<4096, blk, 0, stream>>>(x, attn_scale, hbuf);
  gemm_bt<1, 0, 0><<<dim3(24, 32), blk, 0, stream>>>(hbuf, wqkv, bqkv, nullptr, nullptr, qkvbuf, 4096, 3072, 1024);
  vtrans_k<<<dim3(64, 32, 2), blk, 0, stream>>>(qkvbuf, vtbuf);
  attn_k<<<dim3(32, 32), blk, 0, stream>>>(qkvbuf, vtbuf, aobuf);
  gemm_bt<0, 1, 0><<<dim3(8, 32), blk, 0, stream>>>(aobuf, wo, o_b, x, nullptr, x2, 4096, 1024, 1024);
  // ffn path
  rmsnorm_k<<<4096, blk, 0, stream>>>(x2, ffn_scale, hbuf);
  gemm_bt<1, 0, 0><<<dim3(32, 32), blk, 0, stream>>>(hbuf, wg, gate_b, nullptr, nullptr, gbuf, 4096, 4096, 1024);
  gemm_bt<1, 0, 1><<<dim3(32, 32), blk, 0, stream>>>(hbuf, wu, up_b, nullptr, gbuf, tbuf, 4096, 4096, 1024);
  gemm_bt<0, 1, 0><<<dim3(8, 32), blk, 0, stream>>>(tbuf, wd, down_b, x2, nullptr, (float*)d_out, 4096, 1024, 4096);
}

// Round 3
// 358.496 us; speedup vs baseline: 1.4117x; 1.4117x over previous
//
#include <hip/hip_runtime.h>

#define S_LEN 2048
#define DMODEL 1024
#define NHEADS 16
#define MLPDIM 4096

typedef float f32x4 __attribute__((ext_vector_type(4)));
typedef __bf16 bf16x8 __attribute__((ext_vector_type(8)));
typedef __bf16 bf16x4 __attribute__((ext_vector_type(4)));

__device__ __forceinline__ void gload_lds16(const void* gsrc, void* ldst) {
  __builtin_amdgcn_global_load_lds(
      (const __attribute__((address_space(1))) void*)gsrc,
      (__attribute__((address_space(3))) void*)ldst, 16, 0, 0);
}

// ---------------- transpose + f32->bf16 cast: in [K][N] f32 -> out [N][K] bf16
__global__ __launch_bounds__(256) void transpose_cast_k(
    const float* __restrict__ in, __bf16* __restrict__ out, int K, int N) {
  __shared__ float tile[32][33];
  int n0 = blockIdx.x * 32, k0 = blockIdx.y * 32;
  int tx = threadIdx.x & 31, ty = threadIdx.x >> 5;
#pragma unroll
  for (int r = 0; r < 32; r += 8)
    tile[r + ty][tx] = in[(size_t)(k0 + r + ty) * N + n0 + tx];
  __syncthreads();
#pragma unroll
  for (int r = 0; r < 32; r += 8)
    out[(size_t)(n0 + r + ty) * K + k0 + tx] = (__bf16)tile[tx][r + ty];
}

// ---------------- bf16 transpose of V slice: qkv[4096][3072] cols 2048.. -> vt[b][1024][2048]
__global__ __launch_bounds__(256) void vtrans_k(
    const __bf16* __restrict__ qkv, __bf16* __restrict__ vt) {
  __shared__ __bf16 tile[32][33];
  int s0 = blockIdx.x * 32, c0 = blockIdx.y * 32, b = blockIdx.z;
  int tx = threadIdx.x & 31, ty = threadIdx.x >> 5;
#pragma unroll
  for (int r = 0; r < 32; r += 8)
    tile[r + ty][tx] = qkv[(size_t)(b * S_LEN + s0 + r + ty) * 3072 + 2048 + c0 + tx];
  __syncthreads();
#pragma unroll
  for (int r = 0; r < 32; r += 8)
    vt[(size_t)(b * 1024 + c0 + r + ty) * S_LEN + s0 + tx] = tile[tx][r + ty];
}

__global__ __launch_bounds__(256) void concat3_k(
    const float* __restrict__ a, const float* __restrict__ b,
    const float* __restrict__ c, float* __restrict__ dst) {
  int i = blockIdx.x * 256 + threadIdx.x;
  if (i < 1024) dst[i] = a[i];
  else if (i < 2048) dst[i] = b[i - 1024];
  else if (i < 3072) dst[i] = c[i - 2048];
}

// ---------------- RMSNorm: x f32 [rows][1024] -> bf16, * scale
__global__ __launch_bounds__(256) void rmsnorm_k(
    const float* __restrict__ x, const float* __restrict__ scale,
    __bf16* __restrict__ out) {
  int row = blockIdx.x, tid = threadIdx.x;
  f32x4 v = ((const f32x4*)(x + (size_t)row * DMODEL))[tid];
  float ss = v[0] * v[0] + v[1] * v[1] + v[2] * v[2] + v[3] * v[3];
#pragma unroll
  for (int off = 1; off < 64; off <<= 1) ss += __shfl_xor(ss, off, 64);
  __shared__ float part[4];
  if ((tid & 63) == 0) part[tid >> 6] = ss;
  __syncthreads();
  float tot = part[0] + part[1] + part[2] + part[3];
  float r = rsqrtf(tot * (1.0f / DMODEL) + 1e-6f);
  f32x4 s4 = ((const f32x4*)scale)[tid];
  bf16x4 o;
#pragma unroll
  for (int e = 0; e < 4; ++e) o[e] = (__bf16)(v[e] * r * s4[e]);
  ((bf16x4*)out)[(size_t)row * (DMODEL / 4) + tid] = o;
}

// ---------------- GEMM: C[M][N] = A[M][K](bf16) @ Bt[N][K]^T(bf16) + bias
// 2-phase double-buffered (T3-minimum): stage(t+1) before compute(t), 1 barrier/iter
template <int OUT_BF16, int RESID, int SILU>
__global__ __launch_bounds__(256, 2) void gemm_bt(
    const __bf16* __restrict__ A, const __bf16* __restrict__ Bt,
    const float* __restrict__ bias, const float* __restrict__ resid,
    const __bf16* __restrict__ aux, void* __restrict__ Cout,
    int M, int N, int K) {
  __shared__ __attribute__((aligned(16))) __bf16 As[2][128 * 64];
  __shared__ __attribute__((aligned(16))) __bf16 Bs[2][128 * 64];
  int tid = threadIdx.x, lane = tid & 63, wave = tid >> 6;
  int l15 = lane & 15, g4 = lane >> 4;
  int bm = blockIdx.y * 128, bn = blockIdx.x * 128;
  int wr = wave >> 1, wc = wave & 1;
  f32x4 acc[4][4] = {};
  int srow = lane >> 3, scol = (lane & 7) * 8;
  const __bf16* Abase = A + (size_t)bm * K;
  const __bf16* Bbase = Bt + (size_t)bn * K;

  auto stage = [&](int k0, int bf) {
#pragma unroll
    for (int i = 0; i < 4; ++i) {
      int c = wave * 4 + i;
      int row = c * 8 + srow;
      gload_lds16(Abase + (size_t)row * K + k0 + scol, As[bf] + c * 512);
      gload_lds16(Bbase + (size_t)row * K + k0 + scol, Bs[bf] + c * 512);
    }
  };

  stage(0, 0);
  __syncthreads();
  int bf = 0;
  for (int k0 = 0; k0 < K; k0 += 64) {
    if (k0 + 64 < K) stage(k0 + 64, bf ^ 1);
#pragma unroll
    for (int ks = 0; ks < 2; ++ks) {
      bf16x8 af[4], bfr[4];
#pragma unroll
      for (int m = 0; m < 4; ++m)
        af[m] = *(const bf16x8*)(As[bf] + (wr * 64 + m * 16 + l15) * 64 + ks * 32 + g4 * 8);
#pragma unroll
      for (int n = 0; n < 4; ++n)
        bfr[n] = *(const bf16x8*)(Bs[bf] + (wc * 64 + n * 16 + l15) * 64 + ks * 32 + g4 * 8);
      __builtin_amdgcn_s_setprio(1);
#pragma unroll
      for (int m = 0; m < 4; ++m)
#pragma unroll
        for (int n = 0; n < 4; ++n)
          acc[m][n] = __builtin_amdgcn_mfma_f32_16x16x32_bf16(af[m], bfr[n], acc[m][n], 0, 0, 0);
      __builtin_amdgcn_s_setprio(0);
    }
    __syncthreads();
    bf ^= 1;
  }
  int r0 = bm + wr * 64 + g4 * 4;
  int c0 = bn + wc * 64 + l15;
#pragma unroll
  for (int n = 0; n < 4; ++n) {
    int c = c0 + n * 16;
    float bv = bias[c];
#pragma unroll
    for (int m = 0; m < 4; ++m) {
      int rb = r0 + m * 16;
#pragma unroll
      for (int rg = 0; rg < 4; ++rg) {
        int r = rb + rg;
        size_t idx = (size_t)r * N + c;
        float v = acc[m][n][rg] + bv;
        if (SILU) {
          float gg = (float)aux[idx];
          v *= gg / (1.0f + __expf(-gg));
        }
        if (RESID) v += resid[idx];
        if (OUT_BF16) ((__bf16*)Cout)[idx] = (__bf16)v;
        else ((float*)Cout)[idx] = v;
      }
    }
  }
}

// ---------------- causal flash attention: 8 waves x 16 q-rows, 128-key iters,
// LDS K [128][64] + V^T [64][128] staged via global_load_lds with pre-swizzled
// source (T2 XOR swizzle, rule 21), double-buffered, 1 barrier/iter.
// Softmax fully in-register via swapped QK^T (verified R2 math).
#define SCL2E 0.180336879f /* 0.125 * log2(e) */
__global__ __launch_bounds__(512, 4) void attn_k(
    const __bf16* __restrict__ qkv, const __bf16* __restrict__ vt,
    __bf16* __restrict__ ao) {
  __shared__ __attribute__((aligned(16))) __bf16 Ks[2][128 * 64];
  __shared__ __attribute__((aligned(16))) __bf16 Vs[2][64 * 128];
  int tid = threadIdx.x, lane = tid & 63, w = tid >> 6;
  int l15 = lane & 15, g4 = lane >> 4;
  int bh = blockIdx.x, b = bh >> 4, h = bh & 15;
  int qt = 15 - blockIdx.y;  // longest q-tiles dispatch first
  int qb = qt * 128;
  int qw = qb + w * 16;
  const __bf16* qkvb = qkv + (size_t)b * S_LEN * 3072 + h * 64;
  const __bf16* kgb = qkvb + 1024;
  const __bf16* vtb = vt + (size_t)b * 1024 * S_LEN + (size_t)(h * 64) * S_LEN;

  // Q fragment (B-operand): q = qw+l15, d = 32ks + 8g4 + e
  bf16x8 qf[2];
#pragma unroll
  for (int ks = 0; ks < 2; ++ks)
    qf[ks] = *(const bf16x8*)(qkvb + (size_t)(qw + l15) * 3072 + 32 * ks + 8 * g4);

  f32x4 oa[4] = {};
  float mrow = -1e30f, lrow = 0.f;
  int q = qw + l15;
  int nt = qt + 1;

  // stage 128-key tile: K rows pre-swizzled by (c ^ (r&7)) 16B units; V same.
  auto stage = [&](int kvb, int buf) {
#pragma unroll
    for (int i = 0; i < 2; ++i) {
      int u = tid + i * 512;
      int r = u >> 3, c = u & 7;
      gload_lds16(kgb + (size_t)(kvb + r) * 3072 + ((c ^ (r & 7)) << 3),
                  Ks[buf] + w * 512 + i * 4096);
    }
#pragma unroll
    for (int i = 0; i < 2; ++i) {
      int u = tid + i * 512;
      int r = u >> 4, cu = u & 15;
      gload_lds16(vtb + (size_t)r * S_LEN + kvb + ((cu ^ (r & 7)) << 3),
                  Vs[buf] + w * 512 + i * 4096);
    }
  };

  stage(0, 0);
  __syncthreads();
  int buf = 0;
  for (int t = 0; t < nt; ++t) {
    int kvb = t * 128;
    if (t + 1 < nt) stage(kvb + 128, buf ^ 1);

    // S = K Q^T for 2 sub-tiles of 64 keys
    f32x4 sa[8];
#pragma unroll
    for (int i = 0; i < 8; ++i) sa[i] = f32x4{0.f, 0.f, 0.f, 0.f};
#pragma unroll
    for (int st = 0; st < 2; ++st)
#pragma unroll
      for (int ks = 0; ks < 2; ++ks) {
        bf16x8 kf[4];
#pragma unroll
        for (int n = 0; n < 4; ++n) {
          int rr = st * 64 + n * 16 + l15;
          int bc = (64 * ks + 16 * g4) ^ ((rr & 7) << 4);
          kf[n] = *(const bf16x8*)((const char*)Ks[buf] + rr * 128 + bc);
        }
        __builtin_amdgcn_s_setprio(1);
#pragma unroll
        for (int n = 0; n < 4; ++n)
          sa[st * 4 + n] = __builtin_amdgcn_mfma_f32_16x16x32_bf16(kf[n], qf[ks], sa[st * 4 + n], 0, 0, 0);
        __builtin_amdgcn_s_setprio(0);
      }

    // online softmax over 128 keys (log2 domain), mask only on diagonal tile
    bool lastt = (t == nt - 1);
    float nmx = -1e30f;
#pragma unroll
    for (int i = 0; i < 8; ++i)
#pragma unroll
      for (int rg = 0; rg < 4; ++rg) {
        float s = sa[i][rg] * SCL2E;
        if (lastt) {
          int key = kvb + (i >> 2) * 64 + (i & 3) * 16 + 4 * g4 + rg;
          s = (key <= q) ? s : -1e30f;
        }
        sa[i][rg] = s;
        nmx = fmaxf(nmx, s);
      }
    nmx = fmaxf(nmx, __shfl_xor(nmx, 16));
    nmx = fmaxf(nmx, __shfl_xor(nmx, 32));
    float nm = fmaxf(mrow, nmx);
    float sc = exp2f(mrow - nm);
    mrow = nm;
    float rs = 0.f;
    bf16x8 pa[2][2];  // [st][ks], e = hf*4+rg -> key st*64+32ks+16hf+4g4+rg
#pragma unroll
    for (int st = 0; st < 2; ++st)
#pragma unroll
      for (int ks = 0; ks < 2; ++ks)
#pragma unroll
        for (int hf = 0; hf < 2; ++hf)
#pragma unroll
          for (int rg = 0; rg < 4; ++rg) {
            float p = exp2f(sa[st * 4 + 2 * ks + hf][rg] - nm);
            rs += p;
            pa[st][ks][hf * 4 + rg] = (__bf16)p;
          }
    rs += __shfl_xor(rs, 16);
    rs += __shfl_xor(rs, 32);
    lrow = lrow * sc + rs;
#pragma unroll
    for (int rg = 0; rg < 4; ++rg) {
      float scq = __shfl(sc, 4 * g4 + rg);
#pragma unroll
      for (int dn = 0; dn < 4; ++dn) oa[dn][rg] *= scq;
    }

    // O += P V  (V from swizzled LDS, sigma = 4g4+(e&3)+16(e>>2))
#pragma unroll
    for (int st = 0; st < 2; ++st)
#pragma unroll
      for (int ks = 0; ks < 2; ++ks) {
        __builtin_amdgcn_s_setprio(1);
#pragma unroll
        for (int dn = 0; dn < 4; ++dn) {
          int rr = dn * 16 + l15;
          int swz = (rr & 7) << 4;
          int bb = st * 128 + 64 * ks + 8 * g4;
          const char* vrow = (const char*)Vs[buf] + rr * 256;
          bf16x4 v0 = *(const bf16x4*)(vrow + (bb ^ swz));
          bf16x4 v1 = *(const bf16x4*)(vrow + ((bb + 32) ^ swz));
          bf16x8 vf;
          vf[0] = v0[0]; vf[1] = v0[1]; vf[2] = v0[2]; vf[3] = v0[3];
          vf[4] = v1[0]; vf[5] = v1[1]; vf[6] = v1[2]; vf[7] = v1[3];
          oa[dn] = __builtin_amdgcn_mfma_f32_16x16x32_bf16(pa[st][ks], vf, oa[dn], 0, 0, 0);
        }
        __builtin_amdgcn_s_setprio(0);
      }
    __syncthreads();
    buf ^= 1;
  }

  // epilogue: O[q'=qw+4g4+rg][d=h*64+dn*16+l15]
  __bf16* aobase = ao + (size_t)b * S_LEN * DMODEL + h * 64;
#pragma unroll
  for (int rg = 0; rg < 4; ++rg) {
    float rl = 1.0f / __shfl(lrow, 4 * g4 + rg);
    int qo = qw + 4 * g4 + rg;
#pragma unroll
    for (int dn = 0; dn < 4; ++dn)
      aobase[(size_t)qo * DMODEL + dn * 16 + l15] = (__bf16)(oa[dn][rg] * rl);
  }
}

// ---------------- host side ----------------
#define OFF_WQKV 0
#define OFF_WO 6291456
#define OFF_WG 8388608
#define OFF_WU 16777216
#define OFF_WD 25165824
#define OFF_BQKV 33554432
#define OFF_H 33570816
#define OFF_QKV 41959424
#define OFF_AO 67125248
#define OFF_G OFF_QKV
#define OFF_T 75513856
#define OFF_VT OFF_T /* VT lives in tbuf's region; dead before up-GEMM writes tbuf */
#define OFF_X2 109068288

extern "C" void kernel_launch(void* const* d_in, const int* in_sizes, int n_in,
                              void* d_out, int out_size, void* d_ws, size_t ws_size,
                              hipStream_t stream) {
  (void)in_sizes; (void)n_in; (void)out_size; (void)ws_size;
  const float* x = (const float*)d_in[0];
  const float* attn_scale = (const float*)d_in[2];
  const float* q_w = (const float*)d_in[3];
  const float* q_b = (const float*)d_in[4];
  const float* k_w = (const float*)d_in[5];
  const float* k_b = (const float*)d_in[6];
  const float* v_w = (const float*)d_in[7];
  const float* v_b = (const float*)d_in[8];
  const float* o_w = (const float*)d_in[9];
  const float* o_b = (const float*)d_in[10];
  const float* ffn_scale = (const float*)d_in[11];
  const float* gate_w = (const float*)d_in[12];
  const float* gate_b = (const float*)d_in[13];
  const float* up_w = (const float*)d_in[14];
  const float* up_b = (const float*)d_in[15];
  const float* down_w = (const float*)d_in[16];
  const float* down_b = (const float*)d_in[17];

  char* ws = (char*)d_ws;
  __bf16* wqkv = (__bf16*)(ws + OFF_WQKV);
  __bf16* wo = (__bf16*)(ws + OFF_WO);
  __bf16* wg = (__bf16*)(ws + OFF_WG);
  __bf16* wu = (__bf16*)(ws + OFF_WU);
  __bf16* wd = (__bf16*)(ws + OFF_WD);
  float* bqkv = (float*)(ws + OFF_BQKV);
  __bf16* hbuf = (__bf16*)(ws + OFF_H);
  __bf16* qkvbuf = (__bf16*)(ws + OFF_QKV);
  __bf16* aobuf = (__bf16*)(ws + OFF_AO);
  __bf16* gbuf = (__bf16*)(ws + OFF_G);
  __bf16* tbuf = (__bf16*)(ws + OFF_T);
  __bf16* vtbuf = (__bf16*)(ws + OFF_VT);
  float* x2 = (float*)(ws + OFF_X2);

  dim3 blk(256);
  // weight prep
  transpose_cast_k<<<dim3(32, 32), blk, 0, stream>>>(q_w, wqkv, 1024, 1024);
  transpose_cast_k<<<dim3(32, 32), blk, 0, stream>>>(k_w, wqkv + 1024 * 1024, 1024, 1024);
  transpose_cast_k<<<dim3(32, 32), blk, 0, stream>>>(v_w, wqkv + 2 * 1024 * 1024, 1024, 1024);
  transpose_cast_k<<<dim3(32, 32), blk, 0, stream>>>(o_w, wo, 1024, 1024);
  transpose_cast_k<<<dim3(128, 32), blk, 0, stream>>>(gate_w, wg, 1024, 4096);
  transpose_cast_k<<<dim3(128, 32), blk, 0, stream>>>(up_w, wu, 1024, 4096);
  transpose_cast_k<<<dim3(32, 128), blk, 0, stream>>>(down_w, wd, 4096, 1024);
  concat3_k<<<12, blk, 0, stream>>>(q_b, k_b, v_b, bqkv);
  // attn path
  rmsnorm_k<<<4096, blk, 0, stream>>>(x, attn_scale, hbuf);
  gemm_bt<1, 0, 0><<<dim3(24, 32), blk, 0, stream>>>(hbuf, wqkv, bqkv, nullptr, nullptr, qkvbuf, 4096, 3072, 1024);
  vtrans_k<<<dim3(64, 32, 2), blk, 0, stream>>>(qkvbuf, vtbuf);
  attn_k<<<dim3(32, 16), dim3(512), 0, stream>>>(qkvbuf, vtbuf, aobuf);
  gemm_bt<0, 1, 0><<<dim3(8, 32), blk, 0, stream>>>(aobuf, wo, o_b, x, nullptr, x2, 4096, 1024, 1024);
  // ffn path
  rmsnorm_k<<<4096, blk, 0, stream>>>(x2, ffn_scale, hbuf);
  gemm_bt<1, 0, 0><<<dim3(32, 32), blk, 0, stream>>>(hbuf, wg, gate_b, nullptr, nullptr, gbuf, 4096, 4096, 1024);
  gemm_bt<1, 0, 1><<<dim3(32, 32), blk, 0, stream>>>(hbuf, wu, up_b, nullptr, gbuf, tbuf, 4096, 4096, 1024);
  gemm_bt<0, 1, 0><<<dim3(8, 32), blk, 0, stream>>>(tbuf, wd, down_b, x2, nullptr, (float*)d_out, 4096, 1024, 4096);
}